// Round 13
// baseline (1798.977 us; speedup 1.0000x reference)
//
#include <hip/hip_runtime.h>
#include <stdint.h>

#define T_ 50

typedef float f32x2 __attribute__((ext_vector_type(2)));
typedef float f32x4 __attribute__((ext_vector_type(4)));
typedef short s16x8 __attribute__((ext_vector_type(8)));

// ---------------- workspace byte offsets ----------------
// WIH/WHH packed in MFMA-fragment order:
//   off = w*16384 + gate*4096 + ks*512 + l15*32 + g*8 + j   (elems)
// WINIT packed: off = w*8192 + sel*4096 + ks*512 + l15*32 + g*8 + j
#define WS_WIH   0u          // 262144 elems
#define WS_WHH   524288u     // 262144 elems
#define WS_WINIT 1048576u    // 131072 elems
#define WS_WFC   1310720u    // [256][256] row order (one-time use)
#define WS_GPAD  1441792u    // [32][32] bf16 zero-padded G
#define WS_NEED  1443840u

// ---------------- LDS byte offsets (dynamic, 78592 B) ----------------
#define L_A1   0             // [24][256] bf16 swizzled (Gh)
#define L_A2   24576         // [24][256] bf16 swizzled (Gx)
#define L_XL   49152         // [24][260] bf16 x tile
#define L_ZR   61696         // [256] bf16 zero row
#define L_HST  62208         // [256 unit][32 node] bf16 h stage
#define L_TOT  78592

__device__ __forceinline__ f32x4 mfma16(s16x8 a, s16x8 b, f32x4 c){
  return __builtin_amdgcn_mfma_f32_16x16x32_bf16(a, b, c, 0, 0, 0);
}
__device__ __forceinline__ uint32_t bfbits(float f){
  uint32_t u = __builtin_bit_cast(uint32_t, f);
  u += 0x7FFFu + ((u >> 16) & 1u);   // RNE
  return u >> 16;
}
__device__ __forceinline__ uint32_t pk2bf(float lo, float hi){
  return bfbits(lo) | (bfbits(hi) << 16);
}
#define LOG2E 1.4426950408889634f
__device__ __forceinline__ float fexp2(float x){ return __builtin_amdgcn_exp2f(x); }
__device__ __forceinline__ float frcp_(float x){ return __builtin_amdgcn_rcpf(x); }
__device__ __forceinline__ float fsig(float x){ return frcp_(1.f + fexp2(-LOG2E * x)); }
__device__ __forceinline__ float ftanh_(float x){ return 1.f - 2.f * frcp_(1.f + fexp2(2.f * LOG2E * x)); }

// ---------------- prep: f32 -> bf16, fragment-packed ----------------
__global__ void prep_kernel(const float* __restrict__ G,
                            const float* __restrict__ Wih, const float* __restrict__ Whh,
                            const float* __restrict__ Wh1, const float* __restrict__ Wh2,
                            const float* __restrict__ Wfc, uint8_t* __restrict__ ws)
{
  const int tid = blockIdx.x * blockDim.x + threadIdx.x;
  const int nth = gridDim.x * blockDim.x;
  uint16_t* wih = (uint16_t*)(ws + WS_WIH);
  uint16_t* whh = (uint16_t*)(ws + WS_WHH);
  uint16_t* wini= (uint16_t*)(ws + WS_WINIT);
  uint16_t* wfc = (uint16_t*)(ws + WS_WFC);
  uint16_t* gp  = (uint16_t*)(ws + WS_GPAD);

  for (int i = tid; i < 262144; i += nth){
    int row = i >> 8, col = i & 255;
    int gt = row >> 8, wv = (row >> 4) & 15, l15 = row & 15;
    int ks = col >> 5, gg = (col >> 3) & 3, j = col & 7;
    int off = wv*16384 + gt*4096 + ks*512 + l15*32 + gg*8 + j;
    wih[off] = (uint16_t)bfbits(Wih[i]);
    whh[off] = (uint16_t)bfbits(Whh[i]);
  }
  for (int i = tid; i < 131072; i += nth){
    int row = i >> 8, col = i & 255;
    int sel = row >> 8, u = row & 255;
    int wv = u >> 4, l15 = u & 15;
    int ks = col >> 5, gg = (col >> 3) & 3, j = col & 7;
    int off = wv*8192 + sel*4096 + ks*512 + l15*32 + gg*8 + j;
    float v = (sel == 0) ? Wh1[u*256 + col] : Wh2[u*256 + col];
    wini[off] = (uint16_t)bfbits(v);
  }
  for (int i = tid; i < 65536; i += nth)
    wfc[i] = (uint16_t)bfbits(Wfc[i]);
  for (int i = tid; i < 1024; i += nth){
    int n = i >> 5, m = i & 31;
    gp[i] = (n < 24 && m < 24) ? (uint16_t)bfbits(G[n*24 + m]) : (uint16_t)0;
  }
}

// ---------------- one workgroup per batch, 16 waves, no inter-WG sync ----------------
__global__ void __launch_bounds__(1024, 4)
encoder_kernel(const float* __restrict__ x, const uint8_t* __restrict__ ws,
               float* __restrict__ out,
               const float* __restrict__ bih, const float* __restrict__ bhh,
               const float* __restrict__ bh1, const float* __restrict__ bh2,
               const float* __restrict__ bfc)
{
  extern __shared__ uint8_t smem[];
  uint16_t* A1  = (uint16_t*)(smem + L_A1);
  uint16_t* A2  = (uint16_t*)(smem + L_A2);
  uint16_t* XL  = (uint16_t*)(smem + L_XL);
  uint16_t* ZR  = (uint16_t*)(smem + L_ZR);
  uint16_t* HST = (uint16_t*)(smem + L_HST);

  const int tid = threadIdx.x;
  const int b   = blockIdx.x;
  const int w   = tid >> 6;        // wave 0..15
  const int l   = tid & 63;
  const int l15 = l & 15;
  const int g   = l >> 4;
  const int u   = w*16 + l15;      // unit 0..255
  const int lg  = l15*32 + g*8;    // packed-fragment lane offset

  const uint16_t* WIHW  = (const uint16_t*)(ws + WS_WIH)   + w*16384;
  const uint16_t* WHHW  = (const uint16_t*)(ws + WS_WHH)   + w*16384;
  const uint16_t* WINIW = (const uint16_t*)(ws + WS_WINIT) + w*8192;
  const uint16_t* WFC   = (const uint16_t*)(ws + WS_WFC);
  const uint16_t* GP    = (const uint16_t*)(ws + WS_GPAD);

  for (int i = tid; i < 256;  i += 1024) ZR[i] = 0;
  for (int i = tid; i < 8192; i += 1024) HST[i] = 0;   // node-pad 24-31 vs NaN

  // G A-fragments for both node tiles
  s16x8 gfragM[2];
  gfragM[0] = *(const s16x8*)&GP[(l15     )*32 + g*8];
  gfragM[1] = *(const s16x8*)&GP[(l15 + 16)*32 + g*8];

  const float bb0 = bih[u]     + bhh[u];
  const float bb1 = bih[256+u] + bhh[256+u];
  const float bb2 = bih[512+u] + bhh[512+u];
  const float bb3 = bih[768+u] + bhh[768+u];
  const float bh1l = bh1[u], bh2l = bh2[u], bfcl = bfc[u];

  // A-fragment row pointers (Mt=0 rows 0-15; Mt=1 rows 16-31, >=24 -> ZR)
  const int r1v = (16 + l15) < 24;
  const uint16_t* a1r0 = A1 + l15*256;
  const uint16_t* a1r1 = r1v ? (A1 + (16+l15)*256) : ZR;
  const uint16_t* a2r0 = A2 + l15*256;
  const uint16_t* a2r1 = r1v ? (A2 + (16+l15)*256) : ZR;
  const int swz0 = (l15 & 7) << 3;
  const int swz1 = r1v ? (((16+l15) & 7) << 3) : 0;

  // depth-3 prefetch helpers (all static indexing)
  auto ldw4 = [&](s16x8 dst[4], const uint16_t* Wb, int ks){
    #pragma unroll
    for (int gt = 0; gt < 4; gt++)
      dst[gt] = *(const s16x8*)&Wb[gt*4096 + ks*512 + lg];
  };
  f32x4 acc[4][2];                 // [gate][node tile]
  auto mm8 = [&](const s16x8 pf[4], int ks, const uint16_t* r0, const uint16_t* r1){
    const int kk = ks*32 + g*8;
    s16x8 A0 = *(const s16x8*)&r0[kk ^ swz0];
    s16x8 A1v = *(const s16x8*)&r1[kk ^ swz1];
    #pragma unroll
    for (int gt = 0; gt < 4; gt++){
      acc[gt][0] = mfma16(A0, pf[gt], acc[gt][0]);
      acc[gt][1] = mfma16(A1v, pf[gt], acc[gt][1]);
    }
  };
  // full GEMM phase: depth-3 pipelined over ks=0..7
  auto gemm_phase = [&](const uint16_t* Wb, const uint16_t* r0, const uint16_t* r1){
    s16x8 P0[4], P1[4], P2[4];
    ldw4(P0, Wb, 0); ldw4(P1, Wb, 1); ldw4(P2, Wb, 2);
    mm8(P0, 0, r0, r1); ldw4(P0, Wb, 3);
    mm8(P1, 1, r0, r1); ldw4(P1, Wb, 4);
    mm8(P2, 2, r0, r1); ldw4(P2, Wb, 5);
    mm8(P0, 3, r0, r1); ldw4(P0, Wb, 6);
    mm8(P1, 4, r0, r1); ldw4(P1, Wb, 7);
    mm8(P2, 5, r0, r1);
    mm8(P0, 6, r0, r1);
    mm8(P1, 7, r0, r1);
  };

  // x tile: 6144 f32, 6 per thread as 3x f32x2 (issue-early/write-late)
  auto xld_issue = [&](const float* xt, f32x2 xv[3]){
    #pragma unroll
    for (int p = 0; p < 3; p++)
      xv[p] = *(const f32x2*)(xt + tid*2 + p*2048);
  };
  auto xld_write = [&](const f32x2 xv[3]){
    #pragma unroll
    for (int p = 0; p < 3; p++){
      int e = tid*2 + p*2048;
      int m = e >> 8, f = e & 255;
      *(uint32_t*)&XL[m*260 + f] = pk2bf(xv[p][0], xv[p][1]);
    }
  };

  // Gx[t]: wave's 16-feature column tile, both node tiles -> A2 swizzled
  auto gx_stage = [&](){
    s16x8 bfrag = (s16x8){0,0,0,0,0,0,0,0};
    if (g < 3){
      #pragma unroll
      for (int j = 0; j < 8; j++)
        bfrag[j] = (short)XL[(g*8 + j)*260 + u];
    }
    #pragma unroll
    for (int Mt = 0; Mt < 2; Mt++){
      f32x4 zz = {0.f,0.f,0.f,0.f};
      f32x4 gx = mfma16(gfragM[Mt], bfrag, zz);
      int n0 = Mt*16 + g*4;
      if (n0 < 24){
        uint32_t a01 = pk2bf(gx[0], gx[1]), a23 = pk2bf(gx[2], gx[3]);
        A2[(n0  )*256 + (u ^ (((n0  )&7)<<3))] = (uint16_t)a01;
        A2[(n0+1)*256 + (u ^ (((n0+1)&7)<<3))] = (uint16_t)(a01>>16);
        A2[(n0+2)*256 + (u ^ (((n0+2)&7)<<3))] = (uint16_t)a23;
        A2[(n0+3)*256 + (u ^ (((n0+3)&7)<<3))] = (uint16_t)(a23>>16);
      }
    }
  };

  // Gh from HST -> A1 swizzled
  auto gh_stage = [&](){
    s16x8 hb = *(const s16x8*)&HST[u*32 + g*8];
    #pragma unroll
    for (int Mt = 0; Mt < 2; Mt++){
      f32x4 zz = {0.f,0.f,0.f,0.f};
      f32x4 gh = mfma16(gfragM[Mt], hb, zz);
      int n0 = Mt*16 + g*4;
      if (n0 < 24){
        uint32_t a01 = pk2bf(gh[0], gh[1]), a23 = pk2bf(gh[2], gh[3]);
        A1[(n0  )*256 + (u ^ (((n0  )&7)<<3))] = (uint16_t)a01;
        A1[(n0+1)*256 + (u ^ (((n0+1)&7)<<3))] = (uint16_t)(a01>>16);
        A1[(n0+2)*256 + (u ^ (((n0+2)&7)<<3))] = (uint16_t)a23;
        A1[(n0+3)*256 + (u ^ (((n0+3)&7)<<3))] = (uint16_t)(a23>>16);
      }
    }
  };

  float cst[2][4];
  const float* xb = x + (size_t)b * T_ * 6144;

  // ---------- init ----------
  {
    f32x2 xv[3];
    xld_issue(xb, xv);
    xld_write(xv);
  }
  __syncthreads();                 // XL = x0
  gx_stage();                      // A2 = Gx0
  __syncthreads();
  {
    f32x4 h0a[2] = {{0,0,0,0},{0,0,0,0}}, c0a[2] = {{0,0,0,0},{0,0,0,0}};
    #pragma unroll
    for (int gt = 0; gt < 4; gt++)
      #pragma unroll
      for (int Mt = 0; Mt < 2; Mt++) acc[gt][Mt] = (f32x4){0,0,0,0};
    #pragma unroll 2
    for (int ks = 0; ks < 8; ks++){
      const int kk = ks*32 + g*8;
      s16x8 a0 = *(const s16x8*)&a2r0[kk ^ swz0];
      s16x8 a1 = *(const s16x8*)&a2r1[kk ^ swz1];
      s16x8 b1 = *(const s16x8*)&WINIW[ks*512 + lg];
      s16x8 b2 = *(const s16x8*)&WINIW[4096 + ks*512 + lg];
      h0a[0] = mfma16(a0, b1, h0a[0]);  h0a[1] = mfma16(a1, b1, h0a[1]);
      c0a[0] = mfma16(a0, b2, c0a[0]);  c0a[1] = mfma16(a1, b2, c0a[1]);
      #pragma unroll
      for (int gt = 0; gt < 4; gt++){
        s16x8 bz = *(const s16x8*)&WIHW[gt*4096 + ks*512 + lg];
        acc[gt][0] = mfma16(a0, bz, acc[gt][0]);
        acc[gt][1] = mfma16(a1, bz, acc[gt][1]);
      }
    }
    #pragma unroll
    for (int Mt = 0; Mt < 2; Mt++){
      int n0 = Mt*16 + g*4;
      float hv[4];
      #pragma unroll
      for (int r = 0; r < 4; r++){
        cst[Mt][r] = c0a[Mt][r] + bh2l;
        hv[r]      = h0a[Mt][r] + bh1l;
      }
      if (n0 < 24){
        uint2 p; p.x = pk2bf(hv[0], hv[1]); p.y = pk2bf(hv[2], hv[3]);
        *(uint2*)&HST[u*32 + n0] = p;
      }
    }
  }
  __syncthreads();                 // HST = h0; Gx0 reads done
  gh_stage();                      // A1 = Gh0
  {
    f32x2 xv[3];
    xld_issue(xb + 6144, xv);
    __syncthreads();               // XL free (x0 consumed)
    xld_write(xv);
  }
  __syncthreads();
  gx_stage();                      // A2 = Gx1
  __syncthreads();                 // A1,A2 ready

  // ---------- recurrence: acc holds z_t at loop top ----------
  for (int t = 0; t < T_; t++){
    // u = z_t + Gh_t . W_hh^T   (depth-3 pipelined weight stream)
    gemm_phase(WHHW, a1r0, a1r1);

    // LSTM pointwise -> h to HST
    #pragma unroll
    for (int Mt = 0; Mt < 2; Mt++){
      int n0 = Mt*16 + g*4;
      float hv[4];
      #pragma unroll
      for (int r = 0; r < 4; r++){
        float ig = fsig  (acc[0][Mt][r] + bb0);
        float fg = fsig  (acc[1][Mt][r] + bb1);
        float gg = ftanh_(acc[2][Mt][r] + bb2);
        float og = fsig  (acc[3][Mt][r] + bb3);
        float c  = fg*cst[Mt][r] + ig*gg;
        cst[Mt][r] = c;
        hv[r] = og*ftanh_(c);
      }
      if (n0 < 24){
        uint2 p; p.x = pk2bf(hv[0], hv[1]); p.y = pk2bf(hv[2], hv[3]);
        *(uint2*)&HST[u*32 + n0] = p;
      }
    }
    __syncthreads();               // B1: HST done; A1 reads done
    gh_stage();                    // A1 = Gh_{t+1}

    if (t+1 < T_){
      int tn = (t+2 < T_) ? (t+2) : (T_-1);
      f32x2 xv[3];
      xld_issue(xb + (size_t)tn*6144, xv);   // x_{t+2}, hides under z-GEMM
      // z_{t+1} = Gx_{t+1} . W_ih^T  (depth-3 pipelined)
      #pragma unroll
      for (int gt = 0; gt < 4; gt++)
        #pragma unroll
        for (int Mt = 0; Mt < 2; Mt++) acc[gt][Mt] = (f32x4){0,0,0,0};
      gemm_phase(WIHW, a2r0, a2r1);
      __syncthreads();             // B2: A2/XL reads done; A1 writes done
      xld_write(xv);               // XL = x_{t+2}
      __syncthreads();             // B3: XL ready
      gx_stage();                  // A2 = Gx_{t+2}
    } else {
      __syncthreads();             // B2 (final): A1 writes visible
    }
  }

  // ---------- final: out = tanh(Gh_final . W_fc^T + bfc) ----------
  {
    f32x4 oacc[2] = {{0,0,0,0},{0,0,0,0}};
    #pragma unroll 2
    for (int ks = 0; ks < 8; ks++){
      const int kk = ks*32 + g*8;
      s16x8 a0 = *(const s16x8*)&a1r0[kk ^ swz0];
      s16x8 a1 = *(const s16x8*)&a1r1[kk ^ swz1];
      s16x8 bf = *(const s16x8*)&WFC[u*256 + kk];
      oacc[0] = mfma16(a0, bf, oacc[0]);
      oacc[1] = mfma16(a1, bf, oacc[1]);
    }
    #pragma unroll
    for (int Mt = 0; Mt < 2; Mt++){
      int n0 = Mt*16 + g*4;
      if (n0 < 24){
        #pragma unroll
        for (int r = 0; r < 4; r++)
          out[(size_t)b*6144 + (n0+r)*256 + u] = ftanh_(oacc[Mt][r] + bfcl);
      }
    }
  }
}

extern "C" void kernel_launch(void* const* d_in, const int* in_sizes, int n_in,
                              void* d_out, int out_size, void* d_ws, size_t ws_size,
                              hipStream_t stream)
{
  (void)in_sizes; (void)n_in; (void)out_size;
  if (ws_size < WS_NEED) return;   // loud failure via validation rather than OOB

  const float* x   = (const float*)d_in[0];
  const float* G   = (const float*)d_in[1];
  const float* Wih = (const float*)d_in[2];
  const float* bih = (const float*)d_in[3];
  const float* Whh = (const float*)d_in[4];
  const float* bhh = (const float*)d_in[5];
  const float* Wh1 = (const float*)d_in[6];
  const float* bh1 = (const float*)d_in[7];
  const float* Wh2 = (const float*)d_in[8];
  const float* bh2 = (const float*)d_in[9];
  const float* Wfc = (const float*)d_in[10];
  const float* bfc = (const float*)d_in[11];
  uint8_t* ws = (uint8_t*)d_ws;

  hipLaunchKernelGGL(prep_kernel, dim3(256), dim3(256), 0, stream,
                     G, Wih, Whh, Wh1, Wh2, Wfc, ws);

  hipFuncSetAttribute((const void*)encoder_kernel,
                      hipFuncAttributeMaxDynamicSharedMemorySize, L_TOT);
  hipLaunchKernelGGL(encoder_kernel, dim3(64), dim3(1024), L_TOT, stream,
                     x, (const uint8_t*)ws, (float*)d_out,
                     bih, bhh, bh1, bh2, bfc);
}